// Round 2
// baseline (1141.272 us; speedup 1.0000x reference)
//
#include <hip/hip_runtime.h>

#define SEQ 512
#define BATCH 4096
#define IND 64
#define HID 128
#define MROWS 16

typedef __attribute__((ext_vector_type(4))) float f32x4;
typedef __attribute__((ext_vector_type(8))) __bf16 bf16x8;

__device__ __forceinline__ float tanh_fast(float x) {
    // tanh(x) = 1 - 2/(e^{2x}+1); saturates correctly at +-inf, no clamp needed
    float e = __expf(2.0f * x);
    return 1.0f - __fdividef(2.0f, e + 1.0f);
}

// One block = 16 batch rows, persistent across all 512 timesteps.
// 8 waves (512 thr) -> 2 waves/SIMD; wave w owns output cols [16w,16w+16).
// K = 192 = [x_t(64) | h_{t-1}(128)], mfma_f32_16x16x32_bf16, fp32 accum.
// Weights in VGPRs (6 B-frags/wave). x loaded per-lane direct from global
// (L1-broadcast across waves), prefetched 2 steps deep. h double-buffered LDS.
__global__ __launch_bounds__(512, 2) void rnn_kernel(
    const float* __restrict__ x, const float* __restrict__ Wih,
    const float* __restrict__ bih, const float* __restrict__ Whh,
    const float* __restrict__ bhh, float* __restrict__ out)
{
    // row stride 136 bf16 = 272B: 16B-aligned rows for ds_read_b128
    __shared__ __align__(16) __bf16 hs[2][MROWS][136];

    const int tid  = threadIdx.x;
    const int wave = tid >> 6, lane = tid & 63;
    const int quad = lane >> 4, m16 = lane & 15;
    const int b0 = blockIdx.x * MROWS;
    const int n0 = wave * 16 + m16;          // this lane's output column

    // ---- B fragments (combined [Wih | Whh]^T), 6 K-chunks of 32 ----
    // B[k][n]: n = lane&15, k = quad*8 + j
    bf16x8 bfrag[6];
    #pragma unroll
    for (int kc = 0; kc < 6; ++kc) {
        const int k0 = kc * 32 + quad * 8;
        const float* src = (k0 < IND) ? (Wih + n0 * IND + k0)
                                      : (Whh + n0 * HID + (k0 - IND));
        bf16x8 b;
        #pragma unroll
        for (int j = 0; j < 8; ++j) b[j] = (__bf16)src[j];
        bfrag[kc] = b;
    }

    const float bias = bih[n0] + bhh[n0];

    // ---- h_0 = 0 ----
    {
        unsigned* hz = (unsigned*)&hs[0][0][0];
        for (int i = tid; i < MROWS * 136 / 2; i += 512) hz[i] = 0u;
    }

    // ---- per-lane x A-fragment pointers: row m16, k = kc*32 + quad*8 + j ----
    const float* xg = x + (size_t)(b0 + m16) * IND + quad * 8;
    const size_t xstep = (size_t)BATCH * IND;

    // 2-deep prefetch: slot t&1 holds x_t (16 floats = chunk0 @+0, chunk1 @+32)
    f32x4 xf[2][4];
    #pragma unroll
    for (int s = 0; s < 2; ++s) {
        const float* p = xg + (size_t)s * xstep;
        xf[s][0] = *(const f32x4*)(p);
        xf[s][1] = *(const f32x4*)(p + 4);
        xf[s][2] = *(const f32x4*)(p + 32);
        xf[s][3] = *(const f32x4*)(p + 36);
    }
    __syncthreads();

    #pragma unroll 2
    for (int t = 0; t < SEQ; ++t) {
        const int slot = t & 1;

        // ---- x A-frags from registers (prefetched) ----
        bf16x8 ax[2];
        #pragma unroll
        for (int c = 0; c < 2; ++c)
            #pragma unroll
            for (int j = 0; j < 4; ++j) {
                ax[c][j]     = (__bf16)xf[slot][2 * c][j];
                ax[c][4 + j] = (__bf16)xf[slot][2 * c + 1][j];
            }

        // refill slot with x_{t+2}; stays in flight across the raw barrier
        if (t + 2 < SEQ) {
            const float* p = xg + (size_t)(t + 2) * xstep;
            xf[slot][0] = *(const f32x4*)(p);
            xf[slot][1] = *(const f32x4*)(p + 4);
            xf[slot][2] = *(const f32x4*)(p + 32);
            xf[slot][3] = *(const f32x4*)(p + 36);
        }

        // ---- h A-frags: A[m=lane&15][k=quad*8+j], 4 chunks ----
        const __bf16* hp = &hs[slot][0][0] + m16 * 136 + quad * 8;
        bf16x8 ah[4];
        #pragma unroll
        for (int kc = 0; kc < 4; ++kc) ah[kc] = *(const bf16x8*)(hp + kc * 32);

        f32x4 acc = {0.f, 0.f, 0.f, 0.f};
        acc = __builtin_amdgcn_mfma_f32_16x16x32_bf16(ax[0], bfrag[0], acc, 0, 0, 0);
        acc = __builtin_amdgcn_mfma_f32_16x16x32_bf16(ax[1], bfrag[1], acc, 0, 0, 0);
        #pragma unroll
        for (int kc = 0; kc < 4; ++kc)
            acc = __builtin_amdgcn_mfma_f32_16x16x32_bf16(ah[kc], bfrag[2 + kc], acc, 0, 0, 0);

        // ---- epilogue: C layout col=lane&15, row=quad*4+r ----
        if (t == SEQ - 1) {
            #pragma unroll
            for (int r = 0; r < 4; ++r)
                out[(size_t)(b0 + quad * 4 + r) * HID + n0] = tanh_fast(acc[r] + bias);
        } else {
            __bf16* hw = &hs[slot ^ 1][0][0];
            #pragma unroll
            for (int r = 0; r < 4; ++r)
                hw[(quad * 4 + r) * 136 + n0] = (__bf16)tanh_fast(acc[r] + bias);
        }

        // LDS-only barrier: drain DS ops, leave global x prefetch in flight
        __asm__ __volatile__("s_waitcnt lgkmcnt(0)\n\ts_barrier" ::: "memory");
    }
}

extern "C" void kernel_launch(void* const* d_in, const int* in_sizes, int n_in,
                              void* d_out, int out_size, void* d_ws, size_t ws_size,
                              hipStream_t stream) {
    const float* x   = (const float*)d_in[0];
    const float* Wih = (const float*)d_in[1];
    const float* bih = (const float*)d_in[2];
    const float* Whh = (const float*)d_in[3];
    const float* bhh = (const float*)d_in[4];
    float* out = (float*)d_out;

    dim3 grid(BATCH / MROWS);   // 256 blocks = 1 per CU, 16 batch rows each
    dim3 block(512);            // 8 waves -> 2 waves/SIMD
    hipLaunchKernelGGL(rnn_kernel, grid, block, 0, stream, x, Wih, bih, Whh, bhh, out);
}